// Round 1
// baseline (324.054 us; speedup 1.0000x reference)
//
#include <hip/hip_runtime.h>
#include <hip/hip_bf16.h>
#include <stdint.h>

#define B_TOT 4096
#define D_DIM 512

typedef __attribute__((ext_vector_type(4))) float f32x4;
typedef __attribute__((ext_vector_type(8))) short short8;

__device__ __forceinline__ float gumbelf(float u) {
  // matches reference: -log(-log(u + 1e-12) + 1e-12), all f32
  return -logf(-logf(u + 1e-12f) + 1e-12f);
}

__device__ __forceinline__ unsigned short f2bf(float f) {
  unsigned int u = __float_as_uint(f);
  unsigned int r = u + 0x7fffu + ((u >> 16) & 1u);   // RNE to bf16
  return (unsigned short)(r >> 16);
}

__device__ __forceinline__ void gload_lds16(const void* g, void* l) {
  __builtin_amdgcn_global_load_lds(
      (const __attribute__((address_space(1))) void*)g,
      (__attribute__((address_space(3))) void*)l, 16, 0, 0);
}

// ---------------- kernel 1: sq, bf16 hi/lo split, zero counters --------------
__global__ __launch_bounds__(64) void prep_kernel(
    const float* __restrict__ feat, unsigned short* __restrict__ FH,
    unsigned short* __restrict__ FL, float* __restrict__ sq,
    int* __restrict__ counters) {
  const int i = blockIdx.x;
  const int lane = threadIdx.x;
  const float* row = feat + (size_t)i * D_DIM + lane * 8;
  const float4 a = *(const float4*)row;
  const float4 b = *(const float4*)(row + 4);
  float v[8] = {a.x, a.y, a.z, a.w, b.x, b.y, b.z, b.w};
  float s = 0.f;
  short8 hv, lv;
#pragma unroll
  for (int k = 0; k < 8; ++k) {
    s += v[k] * v[k];
    unsigned short h = f2bf(v[k]);
    float hf = __uint_as_float((unsigned int)h << 16);
    unsigned short l = f2bf(v[k] - hf);
    hv[k] = (short)h;
    lv[k] = (short)l;
  }
  const size_t off = (size_t)i * D_DIM + lane * 8;
  *(short8*)(FH + off) = hv;
  *(short8*)(FL + off) = lv;
#pragma unroll
  for (int m = 32; m >= 1; m >>= 1) s += __shfl_xor(s, m);
  if (lane == 0) {
    sq[i] = s;
    if (i == 0) { counters[0] = 0; counters[1] = 0; }
  }
}

// ---------------- kernel 2: positive sampling (f32 exact) --------------------
__global__ __launch_bounds__(64) void pos_kernel(
    const float* __restrict__ feat, const float* __restrict__ u_pos,
    const float* __restrict__ sq, float* __restrict__ thresh,
    float* __restrict__ score_pos, float* __restrict__ score_pos1) {
  const int i = blockIdx.x;
  const int lane = threadIdx.x;
  const int c0 = i & ~7;
  const float* xr = feat + (size_t)i * D_DIM + lane * 8;
  const float4 x0 = *(const float4*)xr;
  const float4 x1 = *(const float4*)(xr + 4);
  float dj[8];
  const float sqi = sq[i];
#pragma unroll
  for (int jj = 0; jj < 8; ++jj) {
    const int j = c0 + jj;
    const float* yr = feat + (size_t)j * D_DIM + lane * 8;
    const float4 y0 = *(const float4*)yr;
    const float4 y1 = *(const float4*)(yr + 4);
    float p = x0.x * y0.x + x0.y * y0.y + x0.z * y0.z + x0.w * y0.w +
              x1.x * y1.x + x1.y * y1.y + x1.z * y1.z + x1.w * y1.w;
#pragma unroll
    for (int m = 32; m >= 1; m >>= 1) p += __shfl_xor(p, m);
    dj[jj] = fmaxf(sqi + sq[j] - 2.f * p, 1e-8f);
  }
  if (lane == 0) {
    float mx = 0.f, blg = -3e30f, bd = 0.f;
#pragma unroll
    for (int jj = 0; jj < 8; ++jj) {
      const int j = c0 + jj;
      if (j == i) continue;
      mx = fmaxf(mx, dj[jj]);
      const float lg = logf(dj[jj] + 1e-30f) + gumbelf(u_pos[(size_t)i * B_TOT + j]);
      if (lg > blg) { blg = lg; bd = dj[jj]; }
    }
    thresh[i] = bd + 1e-4f;
    score_pos[i] = sqrtf(bd);
    score_pos1[i] = sqrtf(mx);
  }
}

// ------- kernel 3: split-bf16 GEMM (K=1536) + fused negative reduction -------
__global__ __launch_bounds__(256) void neg_kernel(
    const unsigned short* __restrict__ FH, const unsigned short* __restrict__ FL,
    const float* __restrict__ u_neg, const float* __restrict__ sq,
    const float* __restrict__ thresh, float4* __restrict__ part) {
  __shared__ __align__(16) unsigned short As[128 * 64];
  __shared__ __align__(16) unsigned short Bs[128 * 64];
  const int tid = threadIdx.x;
  const int lane = tid & 63;
  const int w = tid >> 6;            // wave 0..3
  const int wrow = w >> 1, wcol = w & 1;
  const int b15 = lane & 15, q = lane >> 4;
  const int i0 = blockIdx.x * 128, jt = blockIdx.y * 128;

  f32x4 acc[4][4];
#pragma unroll
  for (int m = 0; m < 4; ++m)
#pragma unroll
    for (int n = 0; n < 4; ++n) acc[m][n] = (f32x4){0.f, 0.f, 0.f, 0.f};

  const int srow = w * 8 + (lane >> 3);   // +r*32
  const int scol = (lane & 7) * 8;        // bf16 elems (16B)

  for (int kt = 0; kt < 24; ++kt) {
    const int seg = kt >> 3;  // 0: h.h, 1: l.h, 2: h.l
    const unsigned short* Asrc = (seg == 1) ? FL : FH;
    const unsigned short* Bsrc = (seg == 2) ? FL : FH;
    const int kcol = (kt & 7) * 64;
#pragma unroll
    for (int r = 0; r < 4; ++r) {
      gload_lds16(Asrc + (size_t)(i0 + r * 32 + srow) * D_DIM + kcol + scol,
                  (char*)As + r * 4096 + w * 1024);
      gload_lds16(Bsrc + (size_t)(jt + r * 32 + srow) * D_DIM + kcol + scol,
                  (char*)Bs + r * 4096 + w * 1024);
    }
    __syncthreads();
#pragma unroll
    for (int ks = 0; ks < 2; ++ks) {
      short8 af[4], bf[4];
#pragma unroll
      for (int m = 0; m < 4; ++m)
        af[m] = *(const short8*)(As + (wrow * 64 + m * 16 + b15) * 64 + ks * 32 + q * 8);
#pragma unroll
      for (int n = 0; n < 4; ++n)
        bf[n] = *(const short8*)(Bs + (wcol * 64 + n * 16 + b15) * 64 + ks * 32 + q * 8);
#pragma unroll
      for (int m = 0; m < 4; ++m)
#pragma unroll
        for (int n = 0; n < 4; ++n)
          acc[m][n] = __builtin_amdgcn_mfma_f32_16x16x32_bf16(af[m], bf[n], acc[m][n], 0, 0, 0);
    }
    __syncthreads();
  }

  // epilogue: dist + min + masked gumbel-argmax, butterfly per 16-lane group
  float st_min = 3e38f, st_lg = -1e30f, st_d = 0.f;
  int st_ix = 0;
#pragma unroll
  for (int m = 0; m < 4; ++m) {
#pragma unroll
    for (int r = 0; r < 4; ++r) {
      const int gi = i0 + wrow * 64 + m * 16 + q * 4 + r;
      const float sqi = sq[gi];
      const float th = thresh[gi];
      const int cls = gi >> 3;
      float c_min = 3e38f, c_lg = -1e30f, c_d = 0.f;
      int c_ix = 0;
#pragma unroll
      for (int n = 0; n < 4; ++n) {
        const int gj = jt + wcol * 64 + n * 16 + b15;
        if ((gj >> 3) != cls) {
          const float g = acc[m][n][r];
          const float dist = fmaxf(sqi + sq[gj] - 2.f * g, 1e-8f);
          c_min = fminf(c_min, dist);
          if (dist < th) {
            const float lg = gumbelf(u_neg[(size_t)gi * B_TOT + gj]) - dist;
            if (lg > c_lg || (lg == c_lg && gj < c_ix)) { c_lg = lg; c_d = dist; c_ix = gj; }
          }
        }
      }
#pragma unroll
      for (int s = 1; s < 16; s <<= 1) {
        const float omin = __shfl_xor(c_min, s);
        const float olg = __shfl_xor(c_lg, s);
        const float od = __shfl_xor(c_d, s);
        const int oix = __shfl_xor(c_ix, s);
        c_min = fminf(c_min, omin);
        if (olg > c_lg || (olg == c_lg && oix < c_ix)) { c_lg = olg; c_d = od; c_ix = oix; }
      }
      if (b15 == m * 4 + r) { st_min = c_min; st_lg = c_lg; st_d = c_d; st_ix = c_ix; }
    }
  }

  // cross-wcol combine via LDS (reuse As)
  float* red = (float*)As;  // [128][2][4]
  {
    const int ownrow = wrow * 64 + (b15 >> 2) * 16 + q * 4 + (b15 & 3);
    float* slot = red + (ownrow * 2 + wcol) * 4;
    slot[0] = st_min; slot[1] = st_lg; slot[2] = st_d; slot[3] = __int_as_float(st_ix);
  }
  __syncthreads();
  if (tid < 128) {
    const float* s0 = red + (tid * 2 + 0) * 4;
    const float* s1 = red + (tid * 2 + 1) * 4;
    float mn = fminf(s0[0], s1[0]);
    float lg = s0[1], d = s0[2];
    int ix = __float_as_int(s0[3]);
    if (s1[1] > lg || (s1[1] == lg && __float_as_int(s1[3]) < ix)) {
      lg = s1[1]; d = s1[2]; ix = __float_as_int(s1[3]);
    }
    part[(size_t)(i0 + tid) * 32 + blockIdx.y] = make_float4(mn, lg, d, __int_as_float(ix));
  }
}

// ---------------- kernel 4: per-row combine + loss ---------------------------
__global__ __launch_bounds__(256) void fin_kernel(
    const float4* __restrict__ part, const float* __restrict__ feat,
    const float* __restrict__ sq, const float* __restrict__ score_pos,
    const float* __restrict__ score_pos1, float* __restrict__ out,
    int* __restrict__ counters) {
  const int i = blockIdx.x * 256 + threadIdx.x;
  float mn = 3e38f, lg = -2e30f, d = 0.f;
  int ix = 0;
#pragma unroll
  for (int s = 0; s < 32; ++s) {
    const float4 p = part[(size_t)i * 32 + s];
    mn = fminf(mn, p.x);
    if (p.y > lg) { lg = p.y; d = p.z; ix = __float_as_int(p.w); }
  }
  float negd;
  if (lg > -1e29f) {
    negd = d;
  } else {
    // fallback: reference picks column 0 (first dist_neg>0 is always j=0)
    if ((i >> 3) == 0) {
      negd = 1e25f;
    } else {
      float dot = 0.f;
      for (int k = 0; k < D_DIM; ++k) dot += feat[(size_t)i * D_DIM + k] * feat[k];
      negd = fmaxf(sq[i] + sq[0] - 2.f * dot, 1e-8f);
    }
  }
  const float sneg = sqrtf(negd);
  const float sneg1 = sqrtf(mn);
  const float diff = 1e-4f + score_pos[i] - sneg;
  out[i] = diff > 0.f ? diff + log1pf(expf(-diff)) : log1pf(expf(diff));
  const unsigned long long mact = __ballot(diff > 0.f);
  const unsigned long long macc = __ballot(score_pos1[i] < sneg1);
  if ((threadIdx.x & 63) == 0) {
    atomicAdd(counters + 0, (int)__popcll(mact));
    atomicAdd(counters + 1, (int)__popcll(macc));
  }
}

// ---------------- kernel 5: scalars ------------------------------------------
__global__ void scal_kernel(const int* __restrict__ counters, float* __restrict__ out) {
  if (threadIdx.x == 0) {
    out[B_TOT] = (float)counters[0] / (float)B_TOT;
    out[B_TOT + 1] = 100.f * (float)counters[1] / (float)B_TOT;
  }
}

extern "C" void kernel_launch(void* const* d_in, const int* in_sizes, int n_in,
                              void* d_out, int out_size, void* d_ws, size_t ws_size,
                              hipStream_t stream) {
  const float* feat = (const float*)d_in[0];
  const float* u_pos = (const float*)d_in[1];
  const float* u_neg = (const float*)d_in[2];
  float* out = (float*)d_out;
  char* ws = (char*)d_ws;
  unsigned short* FH = (unsigned short*)(ws);                       // 4 MiB
  unsigned short* FL = (unsigned short*)(ws + 4194304);             // 4 MiB
  float* sq = (float*)(ws + 8388608);                               // 16 KB
  float* thresh = (float*)(ws + 8388608 + 16384);                   // 16 KB
  float* score_pos = (float*)(ws + 8388608 + 2 * 16384);            // 16 KB
  float* score_pos1 = (float*)(ws + 8388608 + 3 * 16384);           // 16 KB
  float4* part = (float4*)(ws + 8388608 + 4 * 16384);               // 2 MiB
  int* counters = (int*)(ws + 8388608 + 4 * 16384 + 2097152);

  prep_kernel<<<B_TOT, 64, 0, stream>>>(feat, FH, FL, sq, counters);
  pos_kernel<<<B_TOT, 64, 0, stream>>>(feat, u_pos, sq, thresh, score_pos, score_pos1);
  neg_kernel<<<dim3(32, 32), 256, 0, stream>>>(FH, FL, u_neg, sq, thresh, part);
  fin_kernel<<<16, 256, 0, stream>>>(part, feat, sq, score_pos, score_pos1, out, counters);
  scal_kernel<<<1, 64, 0, stream>>>(counters, out);
}

// Round 4
// 321.578 us; speedup vs baseline: 1.0077x; 1.0077x over previous
//
#include <hip/hip_runtime.h>
#include <hip/hip_bf16.h>
#include <stdint.h>

#define B_TOT 4096
#define D_DIM 512

typedef __attribute__((ext_vector_type(4))) float f32x4;
typedef __attribute__((ext_vector_type(8))) short short8;

__device__ __forceinline__ float gumbelf(float u) {
  // matches reference: -log(-log(u + 1e-12) + 1e-12), all f32
  return -logf(-logf(u + 1e-12f) + 1e-12f);
}

__device__ __forceinline__ unsigned short f2bf(float f) {
  unsigned int u = __float_as_uint(f);
  unsigned int r = u + 0x7fffu + ((u >> 16) & 1u);   // RNE to bf16
  return (unsigned short)(r >> 16);
}

__device__ __forceinline__ void gload_lds16(const void* g, void* l) {
  __builtin_amdgcn_global_load_lds(
      (const __attribute__((address_space(1))) void*)g,
      (__attribute__((address_space(3))) void*)l, 16, 0, 0);
}

// ---------------- kernel 1: sq, bf16 hi/lo split, zero counters --------------
__global__ __launch_bounds__(64) void prep_kernel(
    const float* __restrict__ feat, unsigned short* __restrict__ FH,
    unsigned short* __restrict__ FL, float* __restrict__ sq,
    int* __restrict__ counters) {
  const int i = blockIdx.x;
  const int lane = threadIdx.x;
  const float* row = feat + (size_t)i * D_DIM + lane * 8;
  const float4 a = *(const float4*)row;
  const float4 b = *(const float4*)(row + 4);
  float v[8] = {a.x, a.y, a.z, a.w, b.x, b.y, b.z, b.w};
  float s = 0.f;
  short8 hv, lv;
#pragma unroll
  for (int k = 0; k < 8; ++k) {
    s += v[k] * v[k];
    unsigned short h = f2bf(v[k]);
    float hf = __uint_as_float((unsigned int)h << 16);
    unsigned short l = f2bf(v[k] - hf);
    hv[k] = (short)h;
    lv[k] = (short)l;
  }
  const size_t off = (size_t)i * D_DIM + lane * 8;
  *(short8*)(FH + off) = hv;
  *(short8*)(FL + off) = lv;
#pragma unroll
  for (int m = 32; m >= 1; m >>= 1) s += __shfl_xor(s, m);
  if (lane == 0) {
    sq[i] = s;
    if (i == 0) { counters[0] = 0; counters[1] = 0; }
  }
}

// ---------------- kernel 2: positive sampling (f32 exact) --------------------
__global__ __launch_bounds__(64) void pos_kernel(
    const float* __restrict__ feat, const float* __restrict__ u_pos,
    const float* __restrict__ sq, float* __restrict__ thresh,
    float* __restrict__ score_pos, float* __restrict__ score_pos1) {
  const int i = blockIdx.x;
  const int lane = threadIdx.x;
  const int c0 = i & ~7;
  const float* xr = feat + (size_t)i * D_DIM + lane * 8;
  const float4 x0 = *(const float4*)xr;
  const float4 x1 = *(const float4*)(xr + 4);
  float dj[8];
  const float sqi = sq[i];
#pragma unroll
  for (int jj = 0; jj < 8; ++jj) {
    const int j = c0 + jj;
    const float* yr = feat + (size_t)j * D_DIM + lane * 8;
    const float4 y0 = *(const float4*)yr;
    const float4 y1 = *(const float4*)(yr + 4);
    float p = x0.x * y0.x + x0.y * y0.y + x0.z * y0.z + x0.w * y0.w +
              x1.x * y1.x + x1.y * y1.y + x1.z * y1.z + x1.w * y1.w;
#pragma unroll
    for (int m = 32; m >= 1; m >>= 1) p += __shfl_xor(p, m);
    dj[jj] = fmaxf(sqi + sq[j] - 2.f * p, 1e-8f);
  }
  if (lane == 0) {
    float mx = 0.f, blg = -3e30f, bd = 0.f;
#pragma unroll
    for (int jj = 0; jj < 8; ++jj) {
      const int j = c0 + jj;
      if (j == i) continue;
      mx = fmaxf(mx, dj[jj]);
      const float lg = logf(dj[jj] + 1e-30f) + gumbelf(u_pos[(size_t)i * B_TOT + j]);
      if (lg > blg) { blg = lg; bd = dj[jj]; }
    }
    thresh[i] = bd + 1e-4f;
    score_pos[i] = sqrtf(bd);
    score_pos1[i] = sqrtf(mx);
  }
}

// ------- kernel 3: split-bf16 GEMM (K=1536) + fused negative reduction -------
// 128x128 tile, BK=64, double-buffered LDS, 2-phase prefetch, both-sides
// XOR swizzle (pre-swizzled global source slot + swizzled ds_read slot).
__global__ __launch_bounds__(256) void neg_kernel(
    const unsigned short* __restrict__ FH, const unsigned short* __restrict__ FL,
    const float* __restrict__ u_neg, const float* __restrict__ sq,
    const float* __restrict__ thresh, float4* __restrict__ part) {
  __shared__ __align__(16) unsigned short As[2][128 * 64];
  __shared__ __align__(16) unsigned short Bs[2][128 * 64];
  const int tid = threadIdx.x;
  const int lane = tid & 63;
  const int w = tid >> 6;            // wave 0..3
  const int wrow = w >> 1, wcol = w & 1;
  const int b15 = lane & 15, q = lane >> 4;
  const int i0 = blockIdx.x * 128, jt = blockIdx.y * 128;

  f32x4 acc[4][4];
#pragma unroll
  for (int m = 0; m < 4; ++m)
#pragma unroll
    for (int n = 0; n < 4; ++n) acc[m][n] = (f32x4){0.f, 0.f, 0.f, 0.f};

  const int srow = w * 8 + (lane >> 3);           // +r*32 : LDS row this lane fills
  const int sslot = (lane & 7) ^ (lane >> 3);     // pre-swizzled global 16B slot
  const int xorv = b15 & 7;                       // read-side XOR (same involution)

  auto STAGE = [&](int nb, int kt) {
    const int seg = kt >> 3;  // 0: h.h, 1: l.h, 2: h.l
    const unsigned short* Asrc = (seg == 1) ? FL : FH;
    const unsigned short* Bsrc = (seg == 2) ? FL : FH;
    const int kcol = (kt & 7) * 64 + sslot * 8;
#pragma unroll
    for (int r = 0; r < 4; ++r) {
      gload_lds16(Asrc + (size_t)(i0 + r * 32 + srow) * D_DIM + kcol,
                  (char*)As[nb] + r * 4096 + w * 1024);
      gload_lds16(Bsrc + (size_t)(jt + r * 32 + srow) * D_DIM + kcol,
                  (char*)Bs[nb] + r * 4096 + w * 1024);
    }
  };

  auto COMPUTE = [&](int cb) {
#pragma unroll
    for (int ks = 0; ks < 2; ++ks) {
      short8 af[4], bf[4];
#pragma unroll
      for (int m = 0; m < 4; ++m)
        af[m] = *(const short8*)(&As[cb][(wrow * 64 + m * 16 + b15) * 64 +
                                         (((ks * 4 + q) ^ xorv) * 8)]);
#pragma unroll
      for (int n = 0; n < 4; ++n)
        bf[n] = *(const short8*)(&Bs[cb][(wcol * 64 + n * 16 + b15) * 64 +
                                         (((ks * 4 + q) ^ xorv) * 8)]);
#pragma unroll
      for (int m = 0; m < 4; ++m)
#pragma unroll
        for (int n = 0; n < 4; ++n)
          acc[m][n] = __builtin_amdgcn_mfma_f32_16x16x32_bf16(af[m], bf[n], acc[m][n], 0, 0, 0);
    }
  };

  STAGE(0, 0);
  __syncthreads();           // drains vmcnt(0): buf0 ready
  int cur = 0;
#pragma unroll 1
  for (int kt = 0; kt < 23; ++kt) {
    STAGE(cur ^ 1, kt + 1);  // prefetch next tile (overlaps compute below)
    COMPUTE(cur);
    __syncthreads();         // one barrier per K-step (drains prefetch)
    cur ^= 1;
  }
  COMPUTE(cur);              // cur == 1 here; As[0] is free for reuse below

  // epilogue: dist + min + masked gumbel-argmax, butterfly per 16-lane group
  float st_min = 3e38f, st_lg = -1e30f, st_d = 0.f;
  int st_ix = 0;
#pragma unroll
  for (int m = 0; m < 4; ++m) {
#pragma unroll
    for (int r = 0; r < 4; ++r) {
      const int gi = i0 + wrow * 64 + m * 16 + q * 4 + r;
      const float sqi = sq[gi];
      const float th = thresh[gi];
      const int cls = gi >> 3;
      float c_min = 3e38f, c_lg = -1e30f, c_d = 0.f;
      int c_ix = 0;
#pragma unroll
      for (int n = 0; n < 4; ++n) {
        const int gj = jt + wcol * 64 + n * 16 + b15;
        if ((gj >> 3) != cls) {
          const float g = acc[m][n][r];
          const float dist = fmaxf(sqi + sq[gj] - 2.f * g, 1e-8f);
          c_min = fminf(c_min, dist);
          if (dist < th) {
            const float lg = gumbelf(u_neg[(size_t)gi * B_TOT + gj]) - dist;
            if (lg > c_lg || (lg == c_lg && gj < c_ix)) { c_lg = lg; c_d = dist; c_ix = gj; }
          }
        }
      }
#pragma unroll
      for (int s = 1; s < 16; s <<= 1) {
        const float omin = __shfl_xor(c_min, s);
        const float olg = __shfl_xor(c_lg, s);
        const float od = __shfl_xor(c_d, s);
        const int oix = __shfl_xor(c_ix, s);
        c_min = fminf(c_min, omin);
        if (olg > c_lg || (olg == c_lg && oix < c_ix)) { c_lg = olg; c_d = od; c_ix = oix; }
      }
      if (b15 == m * 4 + r) { st_min = c_min; st_lg = c_lg; st_d = c_d; st_ix = c_ix; }
    }
  }

  // cross-wcol combine via LDS (reuse As[0]; other waves only read As[1] now)
  float* red = (float*)As[0];  // [128][2][4]
  {
    const int ownrow = wrow * 64 + (b15 >> 2) * 16 + q * 4 + (b15 & 3);
    float* slot = red + (ownrow * 2 + wcol) * 4;
    slot[0] = st_min; slot[1] = st_lg; slot[2] = st_d; slot[3] = __int_as_float(st_ix);
  }
  __syncthreads();
  if (tid < 128) {
    const float* s0 = red + (tid * 2 + 0) * 4;
    const float* s1 = red + (tid * 2 + 1) * 4;
    float mn = fminf(s0[0], s1[0]);
    float lg = s0[1], d = s0[2];
    int ix = __float_as_int(s0[3]);
    if (s1[1] > lg || (s1[1] == lg && __float_as_int(s1[3]) < ix)) {
      lg = s1[1]; d = s1[2]; ix = __float_as_int(s1[3]);
    }
    part[(size_t)(i0 + tid) * 32 + blockIdx.y] = make_float4(mn, lg, d, __int_as_float(ix));
  }
}

// ---------------- kernel 4: per-row combine + loss ---------------------------
__global__ __launch_bounds__(256) void fin_kernel(
    const float4* __restrict__ part, const float* __restrict__ feat,
    const float* __restrict__ sq, const float* __restrict__ score_pos,
    const float* __restrict__ score_pos1, float* __restrict__ out,
    int* __restrict__ counters) {
  const int i = blockIdx.x * 256 + threadIdx.x;
  float mn = 3e38f, lg = -2e30f, d = 0.f;
  int ix = 0;
#pragma unroll
  for (int s = 0; s < 32; ++s) {
    const float4 p = part[(size_t)i * 32 + s];
    mn = fminf(mn, p.x);
    if (p.y > lg) { lg = p.y; d = p.z; ix = __float_as_int(p.w); }
  }
  float negd;
  if (lg > -1e29f) {
    negd = d;
  } else {
    // fallback: reference picks column 0 (first dist_neg>0 is always j=0)
    if ((i >> 3) == 0) {
      negd = 1e25f;
    } else {
      float dot = 0.f;
      for (int k = 0; k < D_DIM; ++k) dot += feat[(size_t)i * D_DIM + k] * feat[k];
      negd = fmaxf(sq[i] + sq[0] - 2.f * dot, 1e-8f);
    }
  }
  const float sneg = sqrtf(negd);
  const float sneg1 = sqrtf(mn);
  const float diff = 1e-4f + score_pos[i] - sneg;
  out[i] = diff > 0.f ? diff + log1pf(expf(-diff)) : log1pf(expf(diff));
  const unsigned long long mact = __ballot(diff > 0.f);
  const unsigned long long macc = __ballot(score_pos1[i] < sneg1);
  if ((threadIdx.x & 63) == 0) {
    atomicAdd(counters + 0, (int)__popcll(mact));
    atomicAdd(counters + 1, (int)__popcll(macc));
  }
}

// ---------------- kernel 5: scalars ------------------------------------------
__global__ void scal_kernel(const int* __restrict__ counters, float* __restrict__ out) {
  if (threadIdx.x == 0) {
    out[B_TOT] = (float)counters[0] / (float)B_TOT;
    out[B_TOT + 1] = 100.f * (float)counters[1] / (float)B_TOT;
  }
}

extern "C" void kernel_launch(void* const* d_in, const int* in_sizes, int n_in,
                              void* d_out, int out_size, void* d_ws, size_t ws_size,
                              hipStream_t stream) {
  const float* feat = (const float*)d_in[0];
  const float* u_pos = (const float*)d_in[1];
  const float* u_neg = (const float*)d_in[2];
  float* out = (float*)d_out;
  char* ws = (char*)d_ws;
  unsigned short* FH = (unsigned short*)(ws);                       // 4 MiB
  unsigned short* FL = (unsigned short*)(ws + 4194304);             // 4 MiB
  float* sq = (float*)(ws + 8388608);                               // 16 KB
  float* thresh = (float*)(ws + 8388608 + 16384);                   // 16 KB
  float* score_pos = (float*)(ws + 8388608 + 2 * 16384);            // 16 KB
  float* score_pos1 = (float*)(ws + 8388608 + 3 * 16384);           // 16 KB
  float4* part = (float4*)(ws + 8388608 + 4 * 16384);               // 2 MiB
  int* counters = (int*)(ws + 8388608 + 4 * 16384 + 2097152);

  prep_kernel<<<B_TOT, 64, 0, stream>>>(feat, FH, FL, sq, counters);
  pos_kernel<<<B_TOT, 64, 0, stream>>>(feat, u_pos, sq, thresh, score_pos, score_pos1);
  neg_kernel<<<dim3(32, 32), 256, 0, stream>>>(FH, FL, u_neg, sq, thresh, part);
  fin_kernel<<<16, 256, 0, stream>>>(part, feat, sq, score_pos, score_pos1, out, counters);
  scal_kernel<<<1, 64, 0, stream>>>(counters, out);
}

// Round 5
// 269.026 us; speedup vs baseline: 1.2045x; 1.1953x over previous
//
#include <hip/hip_runtime.h>
#include <hip/hip_bf16.h>
#include <stdint.h>

#define B_TOT 4096
#define D_DIM 512

typedef __attribute__((ext_vector_type(4))) float f32x4;
typedef __attribute__((ext_vector_type(8))) short short8;

__device__ __forceinline__ float gumbelf(float u) {
  // matches reference: -log(-log(u + 1e-12) + 1e-12), all f32
  return -logf(-logf(u + 1e-12f) + 1e-12f);
}

__device__ __forceinline__ unsigned short f2bf(float f) {
  unsigned int u = __float_as_uint(f);
  unsigned int r = u + 0x7fffu + ((u >> 16) & 1u);   // RNE to bf16
  return (unsigned short)(r >> 16);
}

__device__ __forceinline__ void gload_lds16(const void* g, void* l) {
  __builtin_amdgcn_global_load_lds(
      (const __attribute__((address_space(1))) void*)g,
      (__attribute__((address_space(3))) void*)l, 16, 0, 0);
}

// ---------------- kernel 1: sq, bf16 hi/lo split, zero counters --------------
__global__ __launch_bounds__(64) void prep_kernel(
    const float* __restrict__ feat, unsigned short* __restrict__ FH,
    unsigned short* __restrict__ FL, float* __restrict__ sq,
    int* __restrict__ counters) {
  const int i = blockIdx.x;
  const int lane = threadIdx.x;
  const float* row = feat + (size_t)i * D_DIM + lane * 8;
  const float4 a = *(const float4*)row;
  const float4 b = *(const float4*)(row + 4);
  float v[8] = {a.x, a.y, a.z, a.w, b.x, b.y, b.z, b.w};
  float s = 0.f;
  short8 hv, lv;
#pragma unroll
  for (int k = 0; k < 8; ++k) {
    s += v[k] * v[k];
    unsigned short h = f2bf(v[k]);
    float hf = __uint_as_float((unsigned int)h << 16);
    unsigned short l = f2bf(v[k] - hf);
    hv[k] = (short)h;
    lv[k] = (short)l;
  }
  const size_t off = (size_t)i * D_DIM + lane * 8;
  *(short8*)(FH + off) = hv;
  *(short8*)(FL + off) = lv;
#pragma unroll
  for (int m = 32; m >= 1; m >>= 1) s += __shfl_xor(s, m);
  if (lane == 0) {
    sq[i] = s;
    if (i == 0) { counters[0] = 0; counters[1] = 0; counters[2] = 0; }
  }
}

// ---------------- kernel 2: positive sampling (f32 exact) --------------------
__global__ __launch_bounds__(64) void pos_kernel(
    const float* __restrict__ feat, const float* __restrict__ u_pos,
    const float* __restrict__ sq, float* __restrict__ thresh,
    float* __restrict__ score_pos, float* __restrict__ score_pos1) {
  const int i = blockIdx.x;
  const int lane = threadIdx.x;
  const int c0 = i & ~7;
  const float* xr = feat + (size_t)i * D_DIM + lane * 8;
  const float4 x0 = *(const float4*)xr;
  const float4 x1 = *(const float4*)(xr + 4);
  float dj[8];
  const float sqi = sq[i];
#pragma unroll
  for (int jj = 0; jj < 8; ++jj) {
    const int j = c0 + jj;
    const float* yr = feat + (size_t)j * D_DIM + lane * 8;
    const float4 y0 = *(const float4*)yr;
    const float4 y1 = *(const float4*)(yr + 4);
    float p = x0.x * y0.x + x0.y * y0.y + x0.z * y0.z + x0.w * y0.w +
              x1.x * y1.x + x1.y * y1.y + x1.z * y1.z + x1.w * y1.w;
#pragma unroll
    for (int m = 32; m >= 1; m >>= 1) p += __shfl_xor(p, m);
    dj[jj] = fmaxf(sqi + sq[j] - 2.f * p, 1e-8f);
  }
  if (lane == 0) {
    float mx = 0.f, blg = -3e30f, bd = 0.f;
#pragma unroll
    for (int jj = 0; jj < 8; ++jj) {
      const int j = c0 + jj;
      if (j == i) continue;
      mx = fmaxf(mx, dj[jj]);
      const float lg = logf(dj[jj] + 1e-30f) + gumbelf(u_pos[(size_t)i * B_TOT + j]);
      if (lg > blg) { blg = lg; bd = dj[jj]; }
    }
    thresh[i] = bd + 1e-4f;
    score_pos[i] = sqrtf(bd);
    score_pos1[i] = sqrtf(mx);
  }
}

// ------- kernel 3: split-bf16 GEMM (K=1536) + fused negative reduction -------
// 128x128 tile, BK=64, double-buffered LDS, 2-phase prefetch, both-sides
// XOR swizzle. Epilogue: u_neg gathers hoisted into one unconditional burst
// (addresses independent of acc) to break the serial predicated HBM chain.
__global__ __launch_bounds__(256) void neg_kernel(
    const unsigned short* __restrict__ FH, const unsigned short* __restrict__ FL,
    const float* __restrict__ u_neg, const float* __restrict__ sq,
    const float* __restrict__ thresh, float4* __restrict__ part) {
  __shared__ __align__(16) unsigned short As[2][128 * 64];
  __shared__ __align__(16) unsigned short Bs[2][128 * 64];
  const int tid = threadIdx.x;
  const int lane = tid & 63;
  const int w = tid >> 6;            // wave 0..3
  const int wrow = w >> 1, wcol = w & 1;
  const int b15 = lane & 15, q = lane >> 4;
  const int i0 = blockIdx.x * 128, jt = blockIdx.y * 128;

  f32x4 acc[4][4];
#pragma unroll
  for (int m = 0; m < 4; ++m)
#pragma unroll
    for (int n = 0; n < 4; ++n) acc[m][n] = (f32x4){0.f, 0.f, 0.f, 0.f};

  const int srow = w * 8 + (lane >> 3);           // +r*32 : LDS row this lane fills
  const int sslot = (lane & 7) ^ (lane >> 3);     // pre-swizzled global 16B slot
  const int xorv = b15 & 7;                       // read-side XOR (same involution)

  auto STAGE = [&](int nb, int kt) {
    const int seg = kt >> 3;  // 0: h.h, 1: l.h, 2: h.l
    const unsigned short* Asrc = (seg == 1) ? FL : FH;
    const unsigned short* Bsrc = (seg == 2) ? FL : FH;
    const int kcol = (kt & 7) * 64 + sslot * 8;
#pragma unroll
    for (int r = 0; r < 4; ++r) {
      gload_lds16(Asrc + (size_t)(i0 + r * 32 + srow) * D_DIM + kcol,
                  (char*)As[nb] + r * 4096 + w * 1024);
      gload_lds16(Bsrc + (size_t)(jt + r * 32 + srow) * D_DIM + kcol,
                  (char*)Bs[nb] + r * 4096 + w * 1024);
    }
  };

  auto COMPUTE = [&](int cb) {
#pragma unroll
    for (int ks = 0; ks < 2; ++ks) {
      short8 af[4], bf[4];
#pragma unroll
      for (int m = 0; m < 4; ++m)
        af[m] = *(const short8*)(&As[cb][(wrow * 64 + m * 16 + b15) * 64 +
                                         (((ks * 4 + q) ^ xorv) * 8)]);
#pragma unroll
      for (int n = 0; n < 4; ++n)
        bf[n] = *(const short8*)(&Bs[cb][(wcol * 64 + n * 16 + b15) * 64 +
                                         (((ks * 4 + q) ^ xorv) * 8)]);
#pragma unroll
      for (int m = 0; m < 4; ++m)
#pragma unroll
        for (int n = 0; n < 4; ++n)
          acc[m][n] = __builtin_amdgcn_mfma_f32_16x16x32_bf16(af[m], bf[n], acc[m][n], 0, 0, 0);
    }
  };

  STAGE(0, 0);
  __syncthreads();           // drains vmcnt(0): buf0 ready
  int cur = 0;
#pragma unroll 1
  for (int kt = 0; kt < 23; ++kt) {
    STAGE(cur ^ 1, kt + 1);  // prefetch next tile (overlaps compute below)
    COMPUTE(cur);
    __syncthreads();         // one barrier per K-step (drains prefetch)
    cur ^= 1;
  }
  COMPUTE(cur);              // cur == 1 here; As[0] is free for reuse below

  // ---- hoisted u_neg gather burst: all 64 loads issued together -------------
  // (addresses depend only on block/lane ids; breaks the serial predicated
  //  HBM-latency chain that dominated the old epilogue)
  float uval[4][4][4];
#pragma unroll
  for (int m = 0; m < 4; ++m)
#pragma unroll
    for (int r = 0; r < 4; ++r) {
      const size_t rowo = (size_t)(i0 + wrow * 64 + m * 16 + q * 4 + r) * B_TOT;
#pragma unroll
      for (int n = 0; n < 4; ++n)
        uval[m][r][n] = u_neg[rowo + jt + wcol * 64 + n * 16 + b15];
    }

  // epilogue: dist + min + masked gumbel-argmax, butterfly per 16-lane group
  float st_min = 3e38f, st_lg = -1e30f, st_d = 0.f;
  int st_ix = 0;
#pragma unroll
  for (int m = 0; m < 4; ++m) {
#pragma unroll
    for (int r = 0; r < 4; ++r) {
      const int gi = i0 + wrow * 64 + m * 16 + q * 4 + r;
      const float sqi = sq[gi];
      const float th = thresh[gi];
      const int cls = gi >> 3;
      float c_min = 3e38f, c_lg = -1e30f, c_d = 0.f;
      int c_ix = 0;
#pragma unroll
      for (int n = 0; n < 4; ++n) {
        const int gj = jt + wcol * 64 + n * 16 + b15;
        if ((gj >> 3) != cls) {
          const float g = acc[m][n][r];
          const float dist = fmaxf(sqi + sq[gj] - 2.f * g, 1e-8f);
          c_min = fminf(c_min, dist);
          if (dist < th) {
            const float lg = gumbelf(uval[m][r][n]) - dist;
            if (lg > c_lg || (lg == c_lg && gj < c_ix)) { c_lg = lg; c_d = dist; c_ix = gj; }
          }
        }
      }
#pragma unroll
      for (int s = 1; s < 16; s <<= 1) {
        const float omin = __shfl_xor(c_min, s);
        const float olg = __shfl_xor(c_lg, s);
        const float od = __shfl_xor(c_d, s);
        const int oix = __shfl_xor(c_ix, s);
        c_min = fminf(c_min, omin);
        if (olg > c_lg || (olg == c_lg && oix < c_ix)) { c_lg = olg; c_d = od; c_ix = oix; }
      }
      if (b15 == m * 4 + r) { st_min = c_min; st_lg = c_lg; st_d = c_d; st_ix = c_ix; }
    }
  }

  // cross-wcol combine via LDS (reuse As[0]; other waves only read As[1] now)
  float* red = (float*)As[0];  // [128][2][4]
  {
    const int ownrow = wrow * 64 + (b15 >> 2) * 16 + q * 4 + (b15 & 3);
    float* slot = red + (ownrow * 2 + wcol) * 4;
    slot[0] = st_min; slot[1] = st_lg; slot[2] = st_d; slot[3] = __int_as_float(st_ix);
  }
  __syncthreads();
  if (tid < 128) {
    const float* s0 = red + (tid * 2 + 0) * 4;
    const float* s1 = red + (tid * 2 + 1) * 4;
    float mn = fminf(s0[0], s1[0]);
    float lg = s0[1], d = s0[2];
    int ix = __float_as_int(s0[3]);
    if (s1[1] > lg || (s1[1] == lg && __float_as_int(s1[3]) < ix)) {
      lg = s1[1]; d = s1[2]; ix = __float_as_int(s1[3]);
    }
    part[(size_t)(i0 + tid) * 32 + blockIdx.y] = make_float4(mn, lg, d, __int_as_float(ix));
  }
}

// -------- kernel 4: per-row combine + loss + ticketed scalar finalize --------
__global__ __launch_bounds__(256) void fin_kernel(
    const float4* __restrict__ part, const float* __restrict__ feat,
    const float* __restrict__ sq, const float* __restrict__ score_pos,
    const float* __restrict__ score_pos1, float* __restrict__ out,
    int* __restrict__ counters) {
  const int i = blockIdx.x * 256 + threadIdx.x;
  float mn = 3e38f, lg = -2e30f, d = 0.f;
  int ix = 0;
#pragma unroll
  for (int s = 0; s < 32; ++s) {
    const float4 p = part[(size_t)i * 32 + s];
    mn = fminf(mn, p.x);
    if (p.y > lg) { lg = p.y; d = p.z; ix = __float_as_int(p.w); }
  }
  float negd;
  if (lg > -1e29f) {
    negd = d;
  } else {
    // fallback: reference picks column 0 (first dist_neg>0 is always j=0)
    if ((i >> 3) == 0) {
      negd = 1e25f;
    } else {
      float dot = 0.f;
      for (int k = 0; k < D_DIM; ++k) dot += feat[(size_t)i * D_DIM + k] * feat[k];
      negd = fmaxf(sq[i] + sq[0] - 2.f * dot, 1e-8f);
    }
  }
  const float sneg = sqrtf(negd);
  const float sneg1 = sqrtf(mn);
  const float diff = 1e-4f + score_pos[i] - sneg;
  out[i] = diff > 0.f ? diff + log1pf(expf(-diff)) : log1pf(expf(diff));
  const unsigned long long mact = __ballot(diff > 0.f);
  const unsigned long long macc = __ballot(score_pos1[i] < sneg1);
  if ((threadIdx.x & 63) == 0) {
    atomicAdd(counters + 0, (int)__popcll(mact));
    atomicAdd(counters + 1, (int)__popcll(macc));
  }
  // last-block-done ticket: fold the old scal_kernel into this dispatch
  __syncthreads();
  __threadfence();
  if (threadIdx.x == 0) {
    const int t = atomicAdd(counters + 2, 1);
    if (t == (int)gridDim.x - 1) {
      const int a = atomicAdd(counters + 0, 0);   // coherent read (bypass L1)
      const int c = atomicAdd(counters + 1, 0);
      out[B_TOT] = (float)a / (float)B_TOT;
      out[B_TOT + 1] = 100.f * (float)c / (float)B_TOT;
    }
  }
}

extern "C" void kernel_launch(void* const* d_in, const int* in_sizes, int n_in,
                              void* d_out, int out_size, void* d_ws, size_t ws_size,
                              hipStream_t stream) {
  const float* feat = (const float*)d_in[0];
  const float* u_pos = (const float*)d_in[1];
  const float* u_neg = (const float*)d_in[2];
  float* out = (float*)d_out;
  char* ws = (char*)d_ws;
  unsigned short* FH = (unsigned short*)(ws);                       // 4 MiB
  unsigned short* FL = (unsigned short*)(ws + 4194304);             // 4 MiB
  float* sq = (float*)(ws + 8388608);                               // 16 KB
  float* thresh = (float*)(ws + 8388608 + 16384);                   // 16 KB
  float* score_pos = (float*)(ws + 8388608 + 2 * 16384);            // 16 KB
  float* score_pos1 = (float*)(ws + 8388608 + 3 * 16384);           // 16 KB
  float4* part = (float4*)(ws + 8388608 + 4 * 16384);               // 2 MiB
  int* counters = (int*)(ws + 8388608 + 4 * 16384 + 2097152);

  prep_kernel<<<B_TOT, 64, 0, stream>>>(feat, FH, FL, sq, counters);
  pos_kernel<<<B_TOT, 64, 0, stream>>>(feat, u_pos, sq, thresh, score_pos, score_pos1);
  neg_kernel<<<dim3(32, 32), 256, 0, stream>>>(FH, FL, u_neg, sq, thresh, part);
  fin_kernel<<<16, 256, 0, stream>>>(part, feat, sq, score_pos, score_pos1, out, counters);
}

// Round 6
// 266.255 us; speedup vs baseline: 1.2171x; 1.0104x over previous
//
#include <hip/hip_runtime.h>
#include <hip/hip_bf16.h>
#include <stdint.h>

#define B_TOT 4096
#define D_DIM 512

typedef __attribute__((ext_vector_type(4))) float f32x4;
typedef __attribute__((ext_vector_type(8))) short short8;

__device__ __forceinline__ float gumbelf(float u) {
  // fast gumbel: raw v_log_f32 (×ln2). Key perturbation ~1e-6, 100x below the
  // bf16-split dist noise (~2e-4) that already bounds argmax stability.
  return -__logf(-__logf(u + 1e-12f) + 1e-12f);
}

__device__ __forceinline__ unsigned short f2bf(float f) {
  unsigned int u = __float_as_uint(f);
  unsigned int r = u + 0x7fffu + ((u >> 16) & 1u);   // RNE to bf16
  return (unsigned short)(r >> 16);
}

__device__ __forceinline__ void gload_lds16(const void* g, void* l) {
  __builtin_amdgcn_global_load_lds(
      (const __attribute__((address_space(1))) void*)g,
      (__attribute__((address_space(3))) void*)l, 16, 0, 0);
}

// ------ kernel 1: fused bf16 split + sq + positive sampling (f32 exact) ------
// Block i: splits row i to FH/FL, computes dots vs its 8-class rows (computing
// each row's sq locally, bit-identical reduction order to the old prep), then
// lane 0 does the gumbel positive sampling.
__global__ __launch_bounds__(64) void prep_pos_kernel(
    const float* __restrict__ feat, const float* __restrict__ u_pos,
    unsigned short* __restrict__ FH, unsigned short* __restrict__ FL,
    float* __restrict__ sq, float* __restrict__ thresh,
    float* __restrict__ score_pos, float* __restrict__ score_pos1,
    int* __restrict__ counters) {
  const int i = blockIdx.x;
  const int lane = threadIdx.x;
  const int c0 = i & ~7;
  const float* xr = feat + (size_t)i * D_DIM + lane * 8;
  const float4 x0 = *(const float4*)xr;
  const float4 x1 = *(const float4*)(xr + 4);
  float v[8] = {x0.x, x0.y, x0.z, x0.w, x1.x, x1.y, x1.z, x1.w};

  short8 hv, lv;
#pragma unroll
  for (int k = 0; k < 8; ++k) {
    unsigned short h = f2bf(v[k]);
    float hf = __uint_as_float((unsigned int)h << 16);
    unsigned short l = f2bf(v[k] - hf);
    hv[k] = (short)h;
    lv[k] = (short)l;
  }
  const size_t off = (size_t)i * D_DIM + lane * 8;
  *(short8*)(FH + off) = hv;
  *(short8*)(FL + off) = lv;

  float p8[8], s8[8];
#pragma unroll
  for (int jj = 0; jj < 8; ++jj) {
    const float* yr = feat + (size_t)(c0 + jj) * D_DIM + lane * 8;
    const float4 y0 = *(const float4*)yr;
    const float4 y1 = *(const float4*)(yr + 4);
    float yv[8] = {y0.x, y0.y, y0.z, y0.w, y1.x, y1.y, y1.z, y1.w};
    float p = 0.f, s = 0.f;
#pragma unroll
    for (int k = 0; k < 8; ++k) { p += v[k] * yv[k]; s += yv[k] * yv[k]; }
#pragma unroll
    for (int m = 32; m >= 1; m >>= 1) {
      p += __shfl_xor(p, m);
      s += __shfl_xor(s, m);
    }
    p8[jj] = p; s8[jj] = s;
  }
  const float sqi = s8[i & 7];   // == old prep's sq[i] (same accumulation order)
  float dj[8];
#pragma unroll
  for (int jj = 0; jj < 8; ++jj)
    dj[jj] = fmaxf(sqi + s8[jj] - 2.f * p8[jj], 1e-8f);

  if (lane == 0) {
    sq[i] = sqi;
    float mx = 0.f, blg = -3e30f, bd = 0.f;
#pragma unroll
    for (int jj = 0; jj < 8; ++jj) {
      const int j = c0 + jj;
      if (j == i) continue;
      mx = fmaxf(mx, dj[jj]);
      const float lg = __logf(dj[jj] + 1e-30f) + gumbelf(u_pos[(size_t)i * B_TOT + j]);
      if (lg > blg) { blg = lg; bd = dj[jj]; }
    }
    thresh[i] = bd + 1e-4f;
    score_pos[i] = sqrtf(bd);
    score_pos1[i] = sqrtf(mx);
    if (i == 0) { counters[0] = 0; counters[1] = 0; counters[2] = 0; }
  }
}

// ------- kernel 2: split-bf16 GEMM (K=1536) + fused negative reduction -------
// 128x128 tile, BK=64, double-buffered LDS, 2-phase prefetch, both-sides
// XOR swizzle, hoisted u_neg gather burst, fast-gumbel epilogue.
__global__ __launch_bounds__(256) void neg_kernel(
    const unsigned short* __restrict__ FH, const unsigned short* __restrict__ FL,
    const float* __restrict__ u_neg, const float* __restrict__ sq,
    const float* __restrict__ thresh, float4* __restrict__ part) {
  __shared__ __align__(16) unsigned short As[2][128 * 64];
  __shared__ __align__(16) unsigned short Bs[2][128 * 64];
  const int tid = threadIdx.x;
  const int lane = tid & 63;
  const int w = tid >> 6;            // wave 0..3
  const int wrow = w >> 1, wcol = w & 1;
  const int b15 = lane & 15, q = lane >> 4;
  const int i0 = blockIdx.x * 128, jt = blockIdx.y * 128;

  f32x4 acc[4][4];
#pragma unroll
  for (int m = 0; m < 4; ++m)
#pragma unroll
    for (int n = 0; n < 4; ++n) acc[m][n] = (f32x4){0.f, 0.f, 0.f, 0.f};

  const int srow = w * 8 + (lane >> 3);           // +r*32 : LDS row this lane fills
  const int sslot = (lane & 7) ^ (lane >> 3);     // pre-swizzled global 16B slot
  const int xorv = b15 & 7;                       // read-side XOR (same involution)

  auto STAGE = [&](int nb, int kt) {
    const int seg = kt >> 3;  // 0: h.h, 1: l.h, 2: h.l
    const unsigned short* Asrc = (seg == 1) ? FL : FH;
    const unsigned short* Bsrc = (seg == 2) ? FL : FH;
    const int kcol = (kt & 7) * 64 + sslot * 8;
#pragma unroll
    for (int r = 0; r < 4; ++r) {
      gload_lds16(Asrc + (size_t)(i0 + r * 32 + srow) * D_DIM + kcol,
                  (char*)As[nb] + r * 4096 + w * 1024);
      gload_lds16(Bsrc + (size_t)(jt + r * 32 + srow) * D_DIM + kcol,
                  (char*)Bs[nb] + r * 4096 + w * 1024);
    }
  };

  auto COMPUTE = [&](int cb) {
#pragma unroll
    for (int ks = 0; ks < 2; ++ks) {
      short8 af[4], bf[4];
#pragma unroll
      for (int m = 0; m < 4; ++m)
        af[m] = *(const short8*)(&As[cb][(wrow * 64 + m * 16 + b15) * 64 +
                                         (((ks * 4 + q) ^ xorv) * 8)]);
#pragma unroll
      for (int n = 0; n < 4; ++n)
        bf[n] = *(const short8*)(&Bs[cb][(wcol * 64 + n * 16 + b15) * 64 +
                                         (((ks * 4 + q) ^ xorv) * 8)]);
#pragma unroll
      for (int m = 0; m < 4; ++m)
#pragma unroll
        for (int n = 0; n < 4; ++n)
          acc[m][n] = __builtin_amdgcn_mfma_f32_16x16x32_bf16(af[m], bf[n], acc[m][n], 0, 0, 0);
    }
  };

  STAGE(0, 0);
  __syncthreads();           // drains vmcnt(0): buf0 ready
  int cur = 0;
#pragma unroll 1
  for (int kt = 0; kt < 23; ++kt) {
    STAGE(cur ^ 1, kt + 1);  // prefetch next tile (overlaps compute below)
    COMPUTE(cur);
    __syncthreads();         // one barrier per K-step (drains prefetch)
    cur ^= 1;
  }
  COMPUTE(cur);              // cur == 1 here; As[0] is free for reuse below

  // ---- hoisted u_neg gather burst: all 64 loads issued together -------------
  float uval[4][4][4];
#pragma unroll
  for (int m = 0; m < 4; ++m)
#pragma unroll
    for (int r = 0; r < 4; ++r) {
      const size_t rowo = (size_t)(i0 + wrow * 64 + m * 16 + q * 4 + r) * B_TOT;
#pragma unroll
      for (int n = 0; n < 4; ++n)
        uval[m][r][n] = u_neg[rowo + jt + wcol * 64 + n * 16 + b15];
    }

  // epilogue: dist + min + masked gumbel-argmax, butterfly per 16-lane group
  float st_min = 3e38f, st_lg = -1e30f, st_d = 0.f;
  int st_ix = 0;
#pragma unroll
  for (int m = 0; m < 4; ++m) {
#pragma unroll
    for (int r = 0; r < 4; ++r) {
      const int gi = i0 + wrow * 64 + m * 16 + q * 4 + r;
      const float sqi = sq[gi];
      const float th = thresh[gi];
      const int cls = gi >> 3;
      float c_min = 3e38f, c_lg = -1e30f, c_d = 0.f;
      int c_ix = 0;
#pragma unroll
      for (int n = 0; n < 4; ++n) {
        const int gj = jt + wcol * 64 + n * 16 + b15;
        if ((gj >> 3) != cls) {
          const float g = acc[m][n][r];
          const float dist = fmaxf(sqi + sq[gj] - 2.f * g, 1e-8f);
          c_min = fminf(c_min, dist);
          if (dist < th) {
            const float lg = gumbelf(uval[m][r][n]) - dist;
            if (lg > c_lg || (lg == c_lg && gj < c_ix)) { c_lg = lg; c_d = dist; c_ix = gj; }
          }
        }
      }
#pragma unroll
      for (int s = 1; s < 16; s <<= 1) {
        const float omin = __shfl_xor(c_min, s);
        const float olg = __shfl_xor(c_lg, s);
        const float od = __shfl_xor(c_d, s);
        const int oix = __shfl_xor(c_ix, s);
        c_min = fminf(c_min, omin);
        if (olg > c_lg || (olg == c_lg && oix < c_ix)) { c_lg = olg; c_d = od; c_ix = oix; }
      }
      if (b15 == m * 4 + r) { st_min = c_min; st_lg = c_lg; st_d = c_d; st_ix = c_ix; }
    }
  }

  // cross-wcol combine via LDS (reuse As[0]; other waves only read As[1] now)
  float* red = (float*)As[0];  // [128][2][4]
  {
    const int ownrow = wrow * 64 + (b15 >> 2) * 16 + q * 4 + (b15 & 3);
    float* slot = red + (ownrow * 2 + wcol) * 4;
    slot[0] = st_min; slot[1] = st_lg; slot[2] = st_d; slot[3] = __int_as_float(st_ix);
  }
  __syncthreads();
  if (tid < 128) {
    const float* s0 = red + (tid * 2 + 0) * 4;
    const float* s1 = red + (tid * 2 + 1) * 4;
    float mn = fminf(s0[0], s1[0]);
    float lg = s0[1], d = s0[2];
    int ix = __float_as_int(s0[3]);
    if (s1[1] > lg || (s1[1] == lg && __float_as_int(s1[3]) < ix)) {
      lg = s1[1]; d = s1[2]; ix = __float_as_int(s1[3]);
    }
    part[(size_t)(i0 + tid) * 32 + blockIdx.y] = make_float4(mn, lg, d, __int_as_float(ix));
  }
}

// -------- kernel 3: per-row combine + loss + ticketed scalar finalize --------
__global__ __launch_bounds__(256) void fin_kernel(
    const float4* __restrict__ part, const float* __restrict__ feat,
    const float* __restrict__ sq, const float* __restrict__ score_pos,
    const float* __restrict__ score_pos1, float* __restrict__ out,
    int* __restrict__ counters) {
  const int i = blockIdx.x * 256 + threadIdx.x;
  float mn = 3e38f, lg = -2e30f, d = 0.f;
  int ix = 0;
#pragma unroll
  for (int s = 0; s < 32; ++s) {
    const float4 p = part[(size_t)i * 32 + s];
    mn = fminf(mn, p.x);
    if (p.y > lg) { lg = p.y; d = p.z; ix = __float_as_int(p.w); }
  }
  float negd;
  if (lg > -1e29f) {
    negd = d;
  } else {
    // fallback: reference picks column 0 (first dist_neg>0 is always j=0)
    if ((i >> 3) == 0) {
      negd = 1e25f;
    } else {
      float dot = 0.f;
      for (int k = 0; k < D_DIM; ++k) dot += feat[(size_t)i * D_DIM + k] * feat[k];
      negd = fmaxf(sq[i] + sq[0] - 2.f * dot, 1e-8f);
    }
  }
  const float sneg = sqrtf(negd);
  const float sneg1 = sqrtf(mn);
  const float diff = 1e-4f + score_pos[i] - sneg;
  out[i] = diff > 0.f ? diff + log1pf(expf(-diff)) : log1pf(expf(diff));
  const unsigned long long mact = __ballot(diff > 0.f);
  const unsigned long long macc = __ballot(score_pos1[i] < sneg1);
  if ((threadIdx.x & 63) == 0) {
    atomicAdd(counters + 0, (int)__popcll(mact));
    atomicAdd(counters + 1, (int)__popcll(macc));
  }
  // last-block-done ticket: scalar outputs fused into this dispatch
  __syncthreads();
  __threadfence();
  if (threadIdx.x == 0) {
    const int t = atomicAdd(counters + 2, 1);
    if (t == (int)gridDim.x - 1) {
      const int a = atomicAdd(counters + 0, 0);   // coherent read (bypass L1)
      const int c = atomicAdd(counters + 1, 0);
      out[B_TOT] = (float)a / (float)B_TOT;
      out[B_TOT + 1] = 100.f * (float)c / (float)B_TOT;
    }
  }
}

extern "C" void kernel_launch(void* const* d_in, const int* in_sizes, int n_in,
                              void* d_out, int out_size, void* d_ws, size_t ws_size,
                              hipStream_t stream) {
  const float* feat = (const float*)d_in[0];
  const float* u_pos = (const float*)d_in[1];
  const float* u_neg = (const float*)d_in[2];
  float* out = (float*)d_out;
  char* ws = (char*)d_ws;
  unsigned short* FH = (unsigned short*)(ws);                       // 4 MiB
  unsigned short* FL = (unsigned short*)(ws + 4194304);             // 4 MiB
  float* sq = (float*)(ws + 8388608);                               // 16 KB
  float* thresh = (float*)(ws + 8388608 + 16384);                   // 16 KB
  float* score_pos = (float*)(ws + 8388608 + 2 * 16384);            // 16 KB
  float* score_pos1 = (float*)(ws + 8388608 + 3 * 16384);           // 16 KB
  float4* part = (float4*)(ws + 8388608 + 4 * 16384);               // 2 MiB
  int* counters = (int*)(ws + 8388608 + 4 * 16384 + 2097152);

  prep_pos_kernel<<<B_TOT, 64, 0, stream>>>(feat, u_pos, FH, FL, sq, thresh,
                                            score_pos, score_pos1, counters);
  neg_kernel<<<dim3(32, 32), 256, 0, stream>>>(FH, FL, u_neg, sq, thresh, part);
  fin_kernel<<<16, 256, 0, stream>>>(part, feat, sq, score_pos, score_pos1, out, counters);
}

// Round 7
// 247.878 us; speedup vs baseline: 1.3073x; 1.0741x over previous
//
#include <hip/hip_runtime.h>
#include <hip/hip_bf16.h>
#include <stdint.h>

#define B_TOT 4096
#define D_DIM 512

typedef __attribute__((ext_vector_type(4))) float f32x4;
typedef __attribute__((ext_vector_type(8))) short short8;

__device__ __forceinline__ float gumbelf(float u) {
  // fast gumbel: raw v_log_f32 (×ln2). Key perturbation ~1e-6, 100x below the
  // bf16-split dist noise (~2e-4) that already bounds argmax stability.
  return -__logf(-__logf(u + 1e-12f) + 1e-12f);
}

__device__ __forceinline__ unsigned short f2bf(float f) {
  unsigned int u = __float_as_uint(f);
  unsigned int r = u + 0x7fffu + ((u >> 16) & 1u);   // RNE to bf16
  return (unsigned short)(r >> 16);
}

__device__ __forceinline__ void gload_lds16(const void* g, void* l) {
  __builtin_amdgcn_global_load_lds(
      (const __attribute__((address_space(1))) void*)g,
      (__attribute__((address_space(3))) void*)l, 16, 0, 0);
}

// ------ kernel 1: fused bf16 split + sq + positive sampling (f32 exact) ------
__global__ __launch_bounds__(64) void prep_pos_kernel(
    const float* __restrict__ feat, const float* __restrict__ u_pos,
    unsigned short* __restrict__ FH, unsigned short* __restrict__ FL,
    float* __restrict__ sq, float* __restrict__ thresh,
    float* __restrict__ score_pos, float* __restrict__ score_pos1,
    int* __restrict__ counters) {
  const int i = blockIdx.x;
  const int lane = threadIdx.x;
  const int c0 = i & ~7;
  const float* xr = feat + (size_t)i * D_DIM + lane * 8;
  const float4 x0 = *(const float4*)xr;
  const float4 x1 = *(const float4*)(xr + 4);
  float v[8] = {x0.x, x0.y, x0.z, x0.w, x1.x, x1.y, x1.z, x1.w};

  short8 hv, lv;
#pragma unroll
  for (int k = 0; k < 8; ++k) {
    unsigned short h = f2bf(v[k]);
    float hf = __uint_as_float((unsigned int)h << 16);
    unsigned short l = f2bf(v[k] - hf);
    hv[k] = (short)h;
    lv[k] = (short)l;
  }
  const size_t off = (size_t)i * D_DIM + lane * 8;
  *(short8*)(FH + off) = hv;
  *(short8*)(FL + off) = lv;

  float p8[8], s8[8];
#pragma unroll
  for (int jj = 0; jj < 8; ++jj) {
    const float* yr = feat + (size_t)(c0 + jj) * D_DIM + lane * 8;
    const float4 y0 = *(const float4*)yr;
    const float4 y1 = *(const float4*)(yr + 4);
    float yv[8] = {y0.x, y0.y, y0.z, y0.w, y1.x, y1.y, y1.z, y1.w};
    float p = 0.f, s = 0.f;
#pragma unroll
    for (int k = 0; k < 8; ++k) { p += v[k] * yv[k]; s += yv[k] * yv[k]; }
#pragma unroll
    for (int m = 32; m >= 1; m >>= 1) {
      p += __shfl_xor(p, m);
      s += __shfl_xor(s, m);
    }
    p8[jj] = p; s8[jj] = s;
  }
  const float sqi = s8[i & 7];
  float dj[8];
#pragma unroll
  for (int jj = 0; jj < 8; ++jj)
    dj[jj] = fmaxf(sqi + s8[jj] - 2.f * p8[jj], 1e-8f);

  if (lane == 0) {
    sq[i] = sqi;
    float mx = 0.f, blg = -3e30f, bd = 0.f;
#pragma unroll
    for (int jj = 0; jj < 8; ++jj) {
      const int j = c0 + jj;
      if (j == i) continue;
      mx = fmaxf(mx, dj[jj]);
      const float lg = __logf(dj[jj] + 1e-30f) + gumbelf(u_pos[(size_t)i * B_TOT + j]);
      if (lg > blg) { blg = lg; bd = dj[jj]; }
    }
    thresh[i] = bd + 1e-4f;
    score_pos[i] = sqrtf(bd);
    score_pos1[i] = sqrtf(mx);
    if (i == 0) { counters[0] = 0; counters[1] = 0; counters[2] = 0; }
  }
}

// ------- kernel 2: split-bf16 GEMM (K=1536) + fused negative reduction -------
// 128x128 tile, BK=64, double-buffered LDS, XOR swizzle, XCD-chunked block
// swizzle (T1), counted-vmcnt pipeline (T4): prefetch stays in flight across
// the barrier; wait targets loads issued one full iteration earlier.
__global__ __launch_bounds__(256) void neg_kernel(
    const unsigned short* __restrict__ FH, const unsigned short* __restrict__ FL,
    const float* __restrict__ u_neg, const float* __restrict__ sq,
    const float* __restrict__ thresh, float4* __restrict__ part) {
  __shared__ __align__(16) unsigned short As[2][128 * 64];
  __shared__ __align__(16) unsigned short Bs[2][128 * 64];
  const int tid = threadIdx.x;
  const int lane = tid & 63;
  const int w = tid >> 6;            // wave 0..3
  const int wrow = w >> 1, wcol = w & 1;
  const int b15 = lane & 15, q = lane >> 4;

  // T1: 2D-chunked XCD swizzle. lid%8 = XCD (round-robin dispatch); give each
  // XCD a contiguous 8(bx) x 16(by) rectangle -> per-XCD panel footprint
  // ~4-6 MiB instead of the full 8 MiB FH+FL.
  const int lid = blockIdx.y * 32 + blockIdx.x;
  const int xcd = lid & 7, rr = lid >> 3;          // rr: 0..127
  const int bx = (xcd & 3) * 8 + (rr & 7);
  const int by = (xcd >> 2) * 16 + (rr >> 3);
  const int i0 = bx * 128, jt = by * 128;

  f32x4 acc[4][4];
#pragma unroll
  for (int m = 0; m < 4; ++m)
#pragma unroll
    for (int n = 0; n < 4; ++n) acc[m][n] = (f32x4){0.f, 0.f, 0.f, 0.f};

  const int srow = w * 8 + (lane >> 3);           // +r*32 : LDS row this lane fills
  const int sslot = (lane & 7) ^ (lane >> 3);     // pre-swizzled global 16B slot
  const int xorv = b15 & 7;                       // read-side XOR (same involution)

  auto STAGE = [&](int nb, int kt) {
    const int seg = kt >> 3;  // 0: h.h, 1: l.h, 2: h.l
    const unsigned short* Asrc = (seg == 1) ? FL : FH;
    const unsigned short* Bsrc = (seg == 2) ? FL : FH;
    const int kcol = (kt & 7) * 64 + sslot * 8;
#pragma unroll
    for (int r = 0; r < 4; ++r) {
      gload_lds16(Asrc + (size_t)(i0 + r * 32 + srow) * D_DIM + kcol,
                  (char*)As[nb] + r * 4096 + w * 1024);
      gload_lds16(Bsrc + (size_t)(jt + r * 32 + srow) * D_DIM + kcol,
                  (char*)Bs[nb] + r * 4096 + w * 1024);
    }
  };

  auto COMPUTE = [&](int cb) {
#pragma unroll
    for (int ks = 0; ks < 2; ++ks) {
      short8 af[4], bf[4];
#pragma unroll
      for (int m = 0; m < 4; ++m)
        af[m] = *(const short8*)(&As[cb][(wrow * 64 + m * 16 + b15) * 64 +
                                         (((ks * 4 + q) ^ xorv) * 8)]);
#pragma unroll
      for (int n = 0; n < 4; ++n)
        bf[n] = *(const short8*)(&Bs[cb][(wcol * 64 + n * 16 + b15) * 64 +
                                         (((ks * 4 + q) ^ xorv) * 8)]);
#pragma unroll
      for (int m = 0; m < 4; ++m)
#pragma unroll
        for (int n = 0; n < 4; ++n)
          acc[m][n] = __builtin_amdgcn_mfma_f32_16x16x32_bf16(af[m], bf[n], acc[m][n], 0, 0, 0);
    }
  };

  // T4 counted-vmcnt K-loop: per iter, 8 stage loads issued for kt+1; the
  // vmcnt(8) wait covers kt's loads (issued one full iteration earlier).
  STAGE(0, 0);
  int cur = 0;
#pragma unroll 1
  for (int kt = 0; kt < 23; ++kt) {
    asm volatile("" ::: "memory");       // pin: prior ds_reads stay above
    STAGE(cur ^ 1, kt + 1);              // outstanding: 8(cur) + 8(next)
    asm volatile("s_waitcnt vmcnt(8)" ::: "memory");  // cur's 8 landed (mine)
    __builtin_amdgcn_s_barrier();        // everyone's cur landed
    COMPUTE(cur);
    asm volatile("" ::: "memory");
    __builtin_amdgcn_s_barrier();        // all waves done reading cur
    cur ^= 1;
  }
  asm volatile("s_waitcnt vmcnt(0)" ::: "memory");   // last tile landed
  __builtin_amdgcn_s_barrier();

  // hoisted u_neg gather burst (issues overlap the final COMPUTE below)
  float uval[4][4][4];
#pragma unroll
  for (int m = 0; m < 4; ++m)
#pragma unroll
    for (int r = 0; r < 4; ++r) {
      const size_t rowo = (size_t)(i0 + wrow * 64 + m * 16 + q * 4 + r) * B_TOT;
#pragma unroll
      for (int n = 0; n < 4; ++n)
        uval[m][r][n] = u_neg[rowo + jt + wcol * 64 + n * 16 + b15];
    }
  asm volatile("" ::: "memory");         // pin burst issue before final COMPUTE
  COMPUTE(cur);                          // cur == 1; As[0] free for reuse below

  // epilogue: dist + min + masked gumbel-argmax, butterfly per 16-lane group
  float st_min = 3e38f, st_lg = -1e30f, st_d = 0.f;
  int st_ix = 0;
#pragma unroll
  for (int m = 0; m < 4; ++m) {
#pragma unroll
    for (int r = 0; r < 4; ++r) {
      const int gi = i0 + wrow * 64 + m * 16 + q * 4 + r;
      const float sqi = sq[gi];
      const float th = thresh[gi];
      const int cls = gi >> 3;
      float c_min = 3e38f, c_lg = -1e30f, c_d = 0.f;
      int c_ix = 0;
#pragma unroll
      for (int n = 0; n < 4; ++n) {
        const int gj = jt + wcol * 64 + n * 16 + b15;
        if ((gj >> 3) != cls) {
          const float g = acc[m][n][r];
          const float dist = fmaxf(sqi + sq[gj] - 2.f * g, 1e-8f);
          c_min = fminf(c_min, dist);
          if (dist < th) {
            const float lg = gumbelf(uval[m][r][n]) - dist;
            if (lg > c_lg || (lg == c_lg && gj < c_ix)) { c_lg = lg; c_d = dist; c_ix = gj; }
          }
        }
      }
#pragma unroll
      for (int s = 1; s < 16; s <<= 1) {
        const float omin = __shfl_xor(c_min, s);
        const float olg = __shfl_xor(c_lg, s);
        const float od = __shfl_xor(c_d, s);
        const int oix = __shfl_xor(c_ix, s);
        c_min = fminf(c_min, omin);
        if (olg > c_lg || (olg == c_lg && oix < c_ix)) { c_lg = olg; c_d = od; c_ix = oix; }
      }
      if (b15 == m * 4 + r) { st_min = c_min; st_lg = c_lg; st_d = c_d; st_ix = c_ix; }
    }
  }

  // cross-wcol combine via LDS (reuse As[0])
  float* red = (float*)As[0];  // [128][2][4]
  {
    const int ownrow = wrow * 64 + (b15 >> 2) * 16 + q * 4 + (b15 & 3);
    float* slot = red + (ownrow * 2 + wcol) * 4;
    slot[0] = st_min; slot[1] = st_lg; slot[2] = st_d; slot[3] = __int_as_float(st_ix);
  }
  __syncthreads();
  if (tid < 128) {
    const float* s0 = red + (tid * 2 + 0) * 4;
    const float* s1 = red + (tid * 2 + 1) * 4;
    float mn = fminf(s0[0], s1[0]);
    float lg = s0[1], d = s0[2];
    int ix = __float_as_int(s0[3]);
    if (s1[1] > lg || (s1[1] == lg && __float_as_int(s1[3]) < ix)) {
      lg = s1[1]; d = s1[2]; ix = __float_as_int(s1[3]);
    }
    part[(size_t)(i0 + tid) * 32 + by] = make_float4(mn, lg, d, __int_as_float(ix));
  }
}

// -------- kernel 3: per-row combine + loss + ticketed scalar finalize --------
__global__ __launch_bounds__(256) void fin_kernel(
    const float4* __restrict__ part, const float* __restrict__ feat,
    const float* __restrict__ sq, const float* __restrict__ score_pos,
    const float* __restrict__ score_pos1, float* __restrict__ out,
    int* __restrict__ counters) {
  const int i = blockIdx.x * 256 + threadIdx.x;
  float mn = 3e38f, lg = -2e30f, d = 0.f;
  int ix = 0;
#pragma unroll
  for (int s = 0; s < 32; ++s) {
    const float4 p = part[(size_t)i * 32 + s];
    mn = fminf(mn, p.x);
    if (p.y > lg) { lg = p.y; d = p.z; ix = __float_as_int(p.w); }
  }
  float negd;
  if (lg > -1e29f) {
    negd = d;
  } else {
    // fallback: reference picks column 0 (first dist_neg>0 is always j=0)
    if ((i >> 3) == 0) {
      negd = 1e25f;
    } else {
      float dot = 0.f;
      for (int k = 0; k < D_DIM; ++k) dot += feat[(size_t)i * D_DIM + k] * feat[k];
      negd = fmaxf(sq[i] + sq[0] - 2.f * dot, 1e-8f);
    }
  }
  const float sneg = sqrtf(negd);
  const float sneg1 = sqrtf(mn);
  const float diff = 1e-4f + score_pos[i] - sneg;
  out[i] = diff > 0.f ? diff + log1pf(expf(-diff)) : log1pf(expf(diff));
  const unsigned long long mact = __ballot(diff > 0.f);
  const unsigned long long macc = __ballot(score_pos1[i] < sneg1);
  if ((threadIdx.x & 63) == 0) {
    atomicAdd(counters + 0, (int)__popcll(mact));
    atomicAdd(counters + 1, (int)__popcll(macc));
  }
  // last-block-done ticket: scalar outputs fused into this dispatch
  __syncthreads();
  __threadfence();
  if (threadIdx.x == 0) {
    const int t = atomicAdd(counters + 2, 1);
    if (t == (int)gridDim.x - 1) {
      const int a = atomicAdd(counters + 0, 0);   // coherent read (bypass L1)
      const int c = atomicAdd(counters + 1, 0);
      out[B_TOT] = (float)a / (float)B_TOT;
      out[B_TOT + 1] = 100.f * (float)c / (float)B_TOT;
    }
  }
}

extern "C" void kernel_launch(void* const* d_in, const int* in_sizes, int n_in,
                              void* d_out, int out_size, void* d_ws, size_t ws_size,
                              hipStream_t stream) {
  const float* feat = (const float*)d_in[0];
  const float* u_pos = (const float*)d_in[1];
  const float* u_neg = (const float*)d_in[2];
  float* out = (float*)d_out;
  char* ws = (char*)d_ws;
  unsigned short* FH = (unsigned short*)(ws);                       // 4 MiB
  unsigned short* FL = (unsigned short*)(ws + 4194304);             // 4 MiB
  float* sq = (float*)(ws + 8388608);                               // 16 KB
  float* thresh = (float*)(ws + 8388608 + 16384);                   // 16 KB
  float* score_pos = (float*)(ws + 8388608 + 2 * 16384);            // 16 KB
  float* score_pos1 = (float*)(ws + 8388608 + 3 * 16384);           // 16 KB
  float4* part = (float4*)(ws + 8388608 + 4 * 16384);               // 2 MiB
  int* counters = (int*)(ws + 8388608 + 4 * 16384 + 2097152);

  prep_pos_kernel<<<B_TOT, 64, 0, stream>>>(feat, u_pos, FH, FL, sq, thresh,
                                            score_pos, score_pos1, counters);
  neg_kernel<<<dim3(32, 32), 256, 0, stream>>>(FH, FL, u_neg, sq, thresh, part);
  fin_kernel<<<16, 256, 0, stream>>>(part, feat, sq, score_pos, score_pos1, out, counters);
}